// Round 4
// baseline (214.475 us; speedup 1.0000x reference)
//
#include <hip/hip_runtime.h>
#include <stdint.h>

#define THRESH 6.0f
#define MAXOUT 128
#define NOC 32      // outlier-column capacity in the MFMA extension
#define KEXT 128    // ext row (bf16): x=[hi|lo|hi|0], w=[hi|hi|lo|0]; K=96 used

typedef float  floatx4  __attribute__((ext_vector_type(4)));
typedef float  floatx16 __attribute__((ext_vector_type(16)));
typedef short  shortx8  __attribute__((ext_vector_type(8)));
typedef int    intx4    __attribute__((ext_vector_type(4)));
typedef int    intx16   __attribute__((ext_vector_type(16)));
typedef unsigned short ushort_t;

__device__ __forceinline__ ushort_t f2bf(float x) {
    union { float f; uint32_t u; } v; v.f = x;
    return (ushort_t)(v.u >> 16);   // truncation; hi/lo split absorbs the error
}
__device__ __forceinline__ float bf2f(ushort_t b) {
    union { float f; uint32_t u; } v; v.u = ((uint32_t)b) << 16;
    return v.f;
}

// ---------------- K1: column absmax via atomicMax (no partial buffer) -------
// fabsf >= 0, so IEEE float order == u32 order; colmax zeroed by memset.
__global__ __launch_bounds__(256) void colmax_atomic_kernel(
    const float* __restrict__ x, uint32_t* __restrict__ colmax_u,
    int n4, int rows_per_slab) {
    int c4 = blockIdx.x * 256 + threadIdx.x;
    if (c4 >= n4) return;
    int r0 = blockIdx.y * rows_per_slab;
    const floatx4* x4 = (const floatx4*)x;
    floatx4 m = {0.f, 0.f, 0.f, 0.f};
    #pragma unroll 8
    for (int r = r0; r < r0 + rows_per_slab; ++r) {
        floatx4 v = x4[(size_t)r * n4 + c4];
        #pragma unroll
        for (int i = 0; i < 4; ++i) m[i] = fmaxf(m[i], fabsf(v[i]));
    }
    #pragma unroll
    for (int i = 0; i < 4; ++i)
        atomicMax(&colmax_u[c4 * 4 + i], __float_as_uint(m[i]));
}

// ---------------- K2: ballot compaction over finished colmax ----------------
// Order across blocks arbitrary -- numerically irrelevant (as before).
__global__ __launch_bounds__(64) void compact_kernel(
    const float* __restrict__ colmax, int* __restrict__ nout,
    int* __restrict__ oidx, int IN) {
    int lane = threadIdx.x;
    int col = blockIdx.x * 64 + lane;
    float m = (col < IN) ? colmax[col] : 0.f;
    bool p = m > THRESH;
    unsigned long long mask = __ballot(p);
    int cnt = __popcll(mask);
    if (cnt > 0) {
        int base = 0;
        if (lane == 0) base = atomicAdd(nout, cnt);
        base = __shfl(base, 0);
        if (p) {
            int pos = base + __popcll(mask & ((1ull << lane) - 1ull));
            if (pos < MAXOUT) oidx[pos] = col;
        }
    }
}

// ---------------- K3: wave-per-row quantization (registers, no LDS) ---------
template<int NITER>   // NITER = IN/256
__global__ __launch_bounds__(256) void quant_kernel(
    const float* __restrict__ x, const float* __restrict__ w,
    const float* __restrict__ colmax,
    const int* __restrict__ oidx, const int* __restrict__ nout,
    int8_t* __restrict__ xq, int8_t* __restrict__ wq,
    float* __restrict__ xscale, float* __restrict__ wscale,
    ushort_t* __restrict__ xoc2, ushort_t* __restrict__ woc2,
    int IN, int T, int TOTAL) {
    int wid = blockIdx.x * 4 + (threadIdx.x >> 6);
    if (wid >= TOTAL) return;
    int lane = threadIdx.x & 63;
    bool isW = wid >= T;
    int r = isW ? wid - T : wid;
    const float* src = (isW ? w : x) + (size_t)r * IN;
    const floatx4* src4 = (const floatx4*)src;
    const floatx4* cm4 = (const floatx4*)colmax;

    floatx4 rowv[NITER];
    float m = 0.f;
    #pragma unroll
    for (int i = 0; i < NITER; ++i) {
        floatx4 v = src4[i * 64 + lane];
        rowv[i] = v;
        if (isW) {
            #pragma unroll
            for (int k = 0; k < 4; ++k) m = fmaxf(m, fabsf(v[k]));
        } else {
            floatx4 cm = cm4[i * 64 + lane];
            #pragma unroll
            for (int k = 0; k < 4; ++k)
                if (!(cm[k] > THRESH)) m = fmaxf(m, fabsf(v[k]));
        }
    }
    #pragma unroll
    for (int off = 32; off; off >>= 1) m = fmaxf(m, __shfl_down(m, off));
    m = __shfl(m, 0);

    float absmax = fmaxf(m, 1e-6f);
    float inv = 127.0f / absmax, scale = absmax / 127.0f;

    uint32_t* dst = (uint32_t*)((isW ? wq : xq) + (size_t)r * IN);
    #pragma unroll
    for (int i = 0; i < NITER; ++i) {
        floatx4 v = rowv[i];
        if (!isW) {
            floatx4 cm = cm4[i * 64 + lane];   // L1-hot reload
            #pragma unroll
            for (int k = 0; k < 4; ++k) if (cm[k] > THRESH) v[k] = 0.f;
        }
        uint32_t pk = 0;
        #pragma unroll
        for (int k = 0; k < 4; ++k) {
            int q = (int)rintf(fminf(fmaxf(v[k] * inv, -127.f), 127.f));
            pk |= ((uint32_t)(uint8_t)(int8_t)q) << (8 * k);
        }
        dst[i * 64 + lane] = pk;
    }
    if (lane == 0) (isW ? wscale : xscale)[r] = scale;

    // extension row [KEXT=128 bf16]: lane computes entries {2*lane, 2*lane+1}
    int no = *nout; if (no > NOC) no = NOC;
    uint32_t pk = 0;
    #pragma unroll
    for (int s = 0; s < 2; ++s) {
        int e = 2 * lane + s;
        int j = e & 31, part = e >> 5;
        ushort_t val = 0;
        if (j < no && part < 3) {
            float v = src[oidx[j]];            // L1/L2-hot scalar re-read
            if (isW) {
                float q = fminf(fmaxf(rintf(v * inv), -127.f), 127.f);
                v = q * scale;                 // dequantized int8 weight
            }
            ushort_t hi = f2bf(v);
            ushort_t lo = f2bf(v - bf2f(hi));
            if (isW) val = (part == 2) ? lo : hi;        // [hi|hi|lo]
            else     val = (part == 1) ? lo : hi;        // [hi|lo|hi]
        }
        pk |= ((uint32_t)val) << (16 * s);
    }
    ushort_t* ext = (isW ? woc2 : xoc2) + (size_t)r * KEXT;
    ((uint32_t*)ext)[lane] = pk;
}

// Generic fallback (IN not a supported multiple)
__global__ __launch_bounds__(256) void quant_generic_kernel(
    const float* __restrict__ x, const float* __restrict__ w,
    const float* __restrict__ colmax,
    const int* __restrict__ oidx, const int* __restrict__ nout,
    int8_t* __restrict__ xq, int8_t* __restrict__ wq,
    float* __restrict__ xscale, float* __restrict__ wscale,
    ushort_t* __restrict__ xoc2, ushort_t* __restrict__ woc2,
    int IN, int T) {
    __shared__ float red[4];
    int bid = blockIdx.x, tid = threadIdx.x;
    bool isW = bid >= T;
    int r = isW ? bid - T : bid;
    const float* src = (isW ? w : x) + (size_t)r * IN;
    float m = 0.f;
    for (int c = tid; c < IN; c += 256) {
        float v = src[c];
        if (isW || !(colmax[c] > THRESH)) m = fmaxf(m, fabsf(v));
    }
    #pragma unroll
    for (int off = 32; off; off >>= 1) m = fmaxf(m, __shfl_down(m, off));
    if ((tid & 63) == 0) red[tid >> 6] = m;
    __syncthreads();
    m = fmaxf(fmaxf(red[0], red[1]), fmaxf(red[2], red[3]));
    float absmax = fmaxf(m, 1e-6f);
    float inv = 127.0f / absmax, scale = absmax / 127.0f;
    int8_t* dst = (isW ? wq : xq) + (size_t)r * IN;
    for (int c = tid; c < IN; c += 256) {
        float v = src[c];
        if (!isW && colmax[c] > THRESH) v = 0.f;
        dst[c] = (int8_t)(int)rintf(fminf(fmaxf(v * inv, -127.f), 127.f));
    }
    if (tid == 0) (isW ? wscale : xscale)[r] = scale;
    int no = *nout; if (no > NOC) no = NOC;
    ushort_t* ext = (isW ? woc2 : xoc2) + (size_t)r * KEXT;
    if (tid < KEXT) {
        int j = tid & 31, part = tid >> 5;
        ushort_t val = 0;
        if (j < no && part < 3) {
            float v = src[oidx[j]];
            if (isW) { float q = fminf(fmaxf(rintf(v * inv), -127.f), 127.f); v = q * scale; }
            ushort_t hi = f2bf(v);
            ushort_t lo = f2bf(v - bf2f(hi));
            if (isW) val = (part == 2) ? lo : hi; else val = (part == 1) ? lo : hi;
        }
        ext[tid] = val;
    }
}

// ---------------- K4: 32x32x32 i8 MFMA GEMM + bf16 32x32x16 ext -------------
// Frozen from round 3 (counted-vmcnt 2-stage pipeline, 67 -> 56.6us).
// Next planned change: 8-phase interleave (kept separate for attribution).
#define BKB 64   // K-tile bytes/row: 64 int8 (main) == 32 bf16 (ext)

// chunk swizzle: LDS[r][c] holds global[r][c ^ swz(r)] (16B chunks)
__device__ __forceinline__ int swz(int r) { return (r ^ (r >> 2)) & 3; }

template<int TBM, int NTHR>
__device__ __forceinline__ void stage_tiles(const uint8_t* Ab, const uint8_t* Bb,
                                            int strideB, int k0b,
                                            uint8_t* sA, uint8_t* sB, int tid) {
    #pragma unroll
    for (int i = 0; i < (TBM * 4) / NTHR; ++i) {
        int idx = i * NTHR + tid;
        int r = idx >> 2, c = idx & 3;
        int cb = (c ^ swz(r)) * 16;   // fetch permuted chunk -> linear LDS slot
        __builtin_amdgcn_global_load_lds(
            (const __attribute__((address_space(1))) uint32_t*)(Ab + (size_t)r * strideB + k0b + cb),
            (__attribute__((address_space(3))) uint32_t*)(sA + idx * 16), 16, 0, 0);
        __builtin_amdgcn_global_load_lds(
            (const __attribute__((address_space(1))) uint32_t*)(Bb + (size_t)r * strideB + k0b + cb),
            (__attribute__((address_space(3))) uint32_t*)(sB + idx * 16), 16, 0, 0);
    }
}

__device__ __forceinline__ const uint8_t* frag_addr(const uint8_t* s, int row, int C) {
    return s + row * BKB + ((C ^ swz(row)) * 16);
}

union accu_t { intx16 i[2][2]; floatx16 f[2][2]; };

__device__ __forceinline__ void compute_i8(const uint8_t* sA, const uint8_t* sB,
                                           int wm, int wn, int l31, int half,
                                           accu_t& acc) {
    intx4 af[2][2], bf[2][2];
    #pragma unroll
    for (int mt = 0; mt < 2; ++mt)
        #pragma unroll
        for (int ks = 0; ks < 2; ++ks)
            af[mt][ks] = *(const intx4*)frag_addr(sA, wm + mt * 32 + l31, ks * 2 + half);
    #pragma unroll
    for (int nt = 0; nt < 2; ++nt)
        #pragma unroll
        for (int ks = 0; ks < 2; ++ks)
            bf[nt][ks] = *(const intx4*)frag_addr(sB, wn + nt * 32 + l31, ks * 2 + half);
    #pragma unroll
    for (int mt = 0; mt < 2; ++mt)
        #pragma unroll
        for (int nt = 0; nt < 2; ++nt)
            #pragma unroll
            for (int ks = 0; ks < 2; ++ks)
                acc.i[mt][nt] = __builtin_amdgcn_mfma_i32_32x32x32_i8(
                    af[mt][ks], bf[nt][ks], acc.i[mt][nt], 0, 0, 0);
}

__device__ __forceinline__ void compute_bf16(const uint8_t* sA, const uint8_t* sB,
                                             int wm, int wn, int l31, int half,
                                             accu_t& acc) {
    shortx8 af[2][2], bf[2][2];
    #pragma unroll
    for (int mt = 0; mt < 2; ++mt)
        #pragma unroll
        for (int ks = 0; ks < 2; ++ks)
            af[mt][ks] = *(const shortx8*)frag_addr(sA, wm + mt * 32 + l31, ks * 2 + half);
    #pragma unroll
    for (int nt = 0; nt < 2; ++nt)
        #pragma unroll
        for (int ks = 0; ks < 2; ++ks)
            bf[nt][ks] = *(const shortx8*)frag_addr(sB, wn + nt * 32 + l31, ks * 2 + half);
    #pragma unroll
    for (int mt = 0; mt < 2; ++mt)
        #pragma unroll
        for (int nt = 0; nt < 2; ++nt)
            #pragma unroll
            for (int ks = 0; ks < 2; ++ks)
                acc.f[mt][nt] = __builtin_amdgcn_mfma_f32_32x32x16_bf16(
                    af[mt][ks], bf[nt][ks], acc.f[mt][nt], 0, 0, 0);
}

// Pipelined big-path kernel: requires (TBM*4)/NTHR == 1 (2 loads/thread/stage)
// and IN/BKB even and >= 4.
template<int TBM, int TBN, int NTHR>
__global__ __launch_bounds__(NTHR) void gemm_pipe_kernel(
    const int8_t* __restrict__ A,   // xq [T, IN]
    const int8_t* __restrict__ B,   // wq [OUT, IN]
    const float* __restrict__ xscale, const float* __restrict__ wscale,
    const float* __restrict__ bias,
    const ushort_t* __restrict__ xoc2,  // [T, KEXT] bf16
    const ushort_t* __restrict__ woc2,  // [OUT, KEXT] bf16
    float* __restrict__ out, int T, int IN, int OUT)
{
    static_assert((TBM * 4) / NTHR == 1, "vmcnt counting assumes 2 loads/thread/stage");
    __shared__ __attribute__((aligned(16))) uint8_t sA0[TBM * BKB];
    __shared__ __attribute__((aligned(16))) uint8_t sB0[TBN * BKB];
    __shared__ __attribute__((aligned(16))) uint8_t sA1[TBM * BKB];
    __shared__ __attribute__((aligned(16))) uint8_t sB1[TBN * BKB];

    int tid = threadIdx.x;

    // bijective XCD-aware block swizzle (nwg % 8 == 0 on the big path)
    int nwg = gridDim.x * gridDim.y;
    int bid = blockIdx.y * gridDim.x + blockIdx.x;
    if ((nwg & 7) == 0) {
        int cpx = nwg >> 3;
        bid = (bid & 7) * cpx + (bid >> 3);
    }
    int bx = bid % gridDim.x, by = bid / gridDim.x;
    int m0 = by * TBM, n0 = bx * TBN;

    int lane = tid & 63, w = tid >> 6;
    constexpr int WC = TBN / 64;            // waves along N
    int wm = (w / WC) * 64, wn = (w % WC) * 64;
    int l31 = lane & 31, half = lane >> 5;

    accu_t acc;
    #pragma unroll
    for (int mt = 0; mt < 2; ++mt)
        #pragma unroll
        for (int nt = 0; nt < 2; ++nt)
            acc.i[mt][nt] = (intx16)(0);

    const uint8_t* Ab = (const uint8_t*)A + (size_t)m0 * IN;
    const uint8_t* Bb = (const uint8_t*)B + (size_t)n0 * IN;

    int nk = IN / BKB;

    // prologue: two stages in flight (2 loads/thread each)
    stage_tiles<TBM, NTHR>(Ab, Bb, IN, 0, sA0, sB0, tid);
    stage_tiles<TBM, NTHR>(Ab, Bb, IN, BKB, sA1, sB1, tid);

    int kt = 0;
    for (; kt + 2 < nk; kt += 2) {
        // -- even step: buffer 0 --
        asm volatile("s_waitcnt vmcnt(2)" ::: "memory");  // kt's loads landed
        __builtin_amdgcn_s_barrier();                     // ... for ALL waves
        compute_i8(sA0, sB0, wm, wn, l31, half, acc);
        __builtin_amdgcn_s_barrier();                     // all done reading b0
        stage_tiles<TBM, NTHR>(Ab, Bb, IN, (kt + 2) * BKB, sA0, sB0, tid);
        // -- odd step: buffer 1 --
        asm volatile("s_waitcnt vmcnt(2)" ::: "memory");  // kt+1's loads landed
        __builtin_amdgcn_s_barrier();
        compute_i8(sA1, sB1, wm, wn, l31, half, acc);
        __builtin_amdgcn_s_barrier();                     // all done reading b1
        stage_tiles<TBM, NTHR>(Ab, Bb, IN, (kt + 3) * BKB, sA1, sB1, tid);
    }
    // epilogue: last two steps, no restage
    asm volatile("s_waitcnt vmcnt(2)" ::: "memory");
    __builtin_amdgcn_s_barrier();
    compute_i8(sA0, sB0, wm, wn, l31, half, acc);
    asm volatile("s_waitcnt vmcnt(0)" ::: "memory");
    __builtin_amdgcn_s_barrier();
    compute_i8(sA1, sB1, wm, wn, l31, half, acc);

    // in-place dequant + bias: f = (float)i * xs * ws + bias
    // C/D 32x32 layout: col=lane&31, row=(reg&3)+8*(reg>>2)+4*(lane>>5)
    #pragma unroll
    for (int mt = 0; mt < 2; ++mt) {
        floatx4 xsg[4];
        #pragma unroll
        for (int g = 0; g < 4; ++g)
            xsg[g] = *(const floatx4*)(xscale + m0 + wm + mt * 32 + g * 8 + half * 4);
        #pragma unroll
        for (int nt = 0; nt < 2; ++nt) {
            int o = n0 + wn + nt * 32 + l31;
            float s = wscale[o], bv = bias[o];
            #pragma unroll
            for (int reg = 0; reg < 16; ++reg)
                acc.f[mt][nt][reg] =
                    (float)acc.i[mt][nt][reg] * (xsg[reg >> 2][reg & 3] * s) + bv;
        }
    }

    // outlier fp correction: 3 bf16 tiles (K=96 useful), old drain style
    const uint8_t* Ae = (const uint8_t*)xoc2 + (size_t)m0 * (KEXT * 2);
    const uint8_t* Be = (const uint8_t*)woc2 + (size_t)n0 * (KEXT * 2);
    #pragma unroll
    for (int kt2 = 0; kt2 < 3; ++kt2) {
        __syncthreads();   // all waves done with previous buffer reads
        stage_tiles<TBM, NTHR>(Ae, Be, KEXT * 2, kt2 * BKB, sA0, sB0, tid);
        __syncthreads();   // vmcnt(0) drain: ext tile ready
        compute_bf16(sA0, sB0, wm, wn, l31, half, acc);
    }

    // store
    #pragma unroll
    for (int mt = 0; mt < 2; ++mt)
        #pragma unroll
        for (int nt = 0; nt < 2; ++nt) {
            int o = n0 + wn + nt * 32 + l31;
            #pragma unroll
            for (int reg = 0; reg < 16; ++reg) {
                int row = (reg & 3) + 8 * (reg >> 2) + 4 * half;
                int t = m0 + wm + mt * 32 + row;
                out[(size_t)t * OUT + o] = acc.f[mt][nt][reg];
            }
        }
}

// Fallback (non-multiple-of-256 shapes): round-0 verified structure
template<int TBM, int TBN, int NTHR>
__global__ __launch_bounds__(NTHR) void gemm_kernel(
    const int8_t* __restrict__ A, const int8_t* __restrict__ B,
    const float* __restrict__ xscale, const float* __restrict__ wscale,
    const float* __restrict__ bias,
    const ushort_t* __restrict__ xoc2, const ushort_t* __restrict__ woc2,
    float* __restrict__ out, int T, int IN, int OUT)
{
    __shared__ __attribute__((aligned(16))) uint8_t sA[TBM * BKB];
    __shared__ __attribute__((aligned(16))) uint8_t sB[TBN * BKB];

    int tid = threadIdx.x;
    int m0 = blockIdx.y * TBM, n0 = blockIdx.x * TBN;
    int lane = tid & 63, w = tid >> 6;
    constexpr int WC = TBN / 64;
    int wm = (w / WC) * 64, wn = (w % WC) * 64;
    int l31 = lane & 31, half = lane >> 5;

    accu_t acc;
    #pragma unroll
    for (int mt = 0; mt < 2; ++mt)
        #pragma unroll
        for (int nt = 0; nt < 2; ++nt)
            acc.i[mt][nt] = (intx16)(0);

    const uint8_t* Ab = (const uint8_t*)A + (size_t)m0 * IN;
    const uint8_t* Bb = (const uint8_t*)B + (size_t)n0 * IN;

    int nk = IN / BKB;
    for (int kt = 0; kt < nk; ++kt) {
        __syncthreads();
        stage_tiles<TBM, NTHR>(Ab, Bb, IN, kt * BKB, sA, sB, tid);
        __syncthreads();
        compute_i8(sA, sB, wm, wn, l31, half, acc);
    }

    #pragma unroll
    for (int mt = 0; mt < 2; ++mt) {
        floatx4 xsg[4];
        #pragma unroll
        for (int g = 0; g < 4; ++g)
            xsg[g] = *(const floatx4*)(xscale + m0 + wm + mt * 32 + g * 8 + half * 4);
        #pragma unroll
        for (int nt = 0; nt < 2; ++nt) {
            int o = n0 + wn + nt * 32 + l31;
            float s = wscale[o], bv = bias[o];
            #pragma unroll
            for (int reg = 0; reg < 16; ++reg)
                acc.f[mt][nt][reg] =
                    (float)acc.i[mt][nt][reg] * (xsg[reg >> 2][reg & 3] * s) + bv;
        }
    }

    const uint8_t* Ae = (const uint8_t*)xoc2 + (size_t)m0 * (KEXT * 2);
    const uint8_t* Be = (const uint8_t*)woc2 + (size_t)n0 * (KEXT * 2);
    #pragma unroll
    for (int kt = 0; kt < 3; ++kt) {
        __syncthreads();
        stage_tiles<TBM, NTHR>(Ae, Be, KEXT * 2, kt * BKB, sA, sB, tid);
        __syncthreads();
        compute_bf16(sA, sB, wm, wn, l31, half, acc);
    }

    #pragma unroll
    for (int mt = 0; mt < 2; ++mt)
        #pragma unroll
        for (int nt = 0; nt < 2; ++nt) {
            int o = n0 + wn + nt * 32 + l31;
            #pragma unroll
            for (int reg = 0; reg < 16; ++reg) {
                int row = (reg & 3) + 8 * (reg >> 2) + 4 * half;
                int t = m0 + wm + mt * 32 + row;
                out[(size_t)t * OUT + o] = acc.f[mt][nt][reg];
            }
        }
}

extern "C" void kernel_launch(void* const* d_in, const int* in_sizes, int n_in,
                              void* d_out, int out_size, void* d_ws, size_t ws_size,
                              hipStream_t stream) {
    const float* x    = (const float*)d_in[0];
    const float* wgt  = (const float*)d_in[1];
    const float* bias = (const float*)d_in[2];
    float* out = (float*)d_out;

    int OUT = in_sizes[2];
    int IN  = in_sizes[1] / OUT;
    int T   = in_sizes[0] / IN;

    char* p = (char*)d_ws;
    int8_t* xq     = (int8_t*)p;   p += (size_t)T * IN;
    int8_t* wq     = (int8_t*)p;   p += (size_t)OUT * IN;
    ushort_t* xoc2 = (ushort_t*)p; p += (size_t)T * KEXT * 2;
    ushort_t* woc2 = (ushort_t*)p; p += (size_t)OUT * KEXT * 2;
    float* wscale  = (float*)p;    p += (size_t)OUT * 4;
    float* xscale  = (float*)p;    p += (size_t)T * 4;
    float* colmax  = (float*)p;    p += (size_t)IN * 4;   // colmax..nout contiguous
    int*   nout    = (int*)p;      p += 256;
    int*   oidx    = (int*)p;      p += MAXOUT * 4;

    // zero colmax (atomicMax identity) + nout in one memset (graph-safe)
    hipMemsetAsync(colmax, 0, (size_t)IN * 4 + 256, stream);

    int n4 = IN / 4;
    int gx = (n4 + 255) / 256;
    int rps = (T % 32 == 0) ? 32 : 1;          // rows per thread-strip
    colmax_atomic_kernel<<<dim3(gx, T / rps), dim3(256), 0, stream>>>(
        x, (uint32_t*)colmax, n4, rps);

    compact_kernel<<<dim3((IN + 63) / 64), dim3(64), 0, stream>>>(
        colmax, nout, oidx, IN);

    int TOTAL = T + OUT;
    int niter = IN / 256;
    bool ok = (IN % 256 == 0) && (niter == 4 || niter == 8 || niter == 16);
    if (ok) {
        int blocks = (TOTAL + 3) / 4;
        switch (niter) {
        case 4:
            quant_kernel<4><<<dim3(blocks), dim3(256), 0, stream>>>(
                x, wgt, colmax, oidx, nout, xq, wq, xscale, wscale, xoc2, woc2, IN, T, TOTAL);
            break;
        case 8:
            quant_kernel<8><<<dim3(blocks), dim3(256), 0, stream>>>(
                x, wgt, colmax, oidx, nout, xq, wq, xscale, wscale, xoc2, woc2, IN, T, TOTAL);
            break;
        default:
            quant_kernel<16><<<dim3(blocks), dim3(256), 0, stream>>>(
                x, wgt, colmax, oidx, nout, xq, wq, xscale, wscale, xoc2, woc2, IN, T, TOTAL);
            break;
        }
    } else {
        quant_generic_kernel<<<dim3(TOTAL), dim3(256), 0, stream>>>(
            x, wgt, colmax, oidx, nout, xq, wq, xscale, wscale, xoc2, woc2, IN, T);
    }

    int nk = IN / BKB;
    bool big = (T % 256 == 0) && (OUT % 256 == 0) && (IN % BKB == 0)
               && (nk % 2 == 0) && (nk >= 4);
    if (big) {
        gemm_pipe_kernel<256, 256, 1024><<<dim3(OUT / 256, T / 256), dim3(1024), 0, stream>>>(
            xq, wq, xscale, wscale, bias, xoc2, woc2, out, T, IN, OUT);
    } else {
        gemm_kernel<128, 128, 256><<<dim3(OUT / 128, T / 128), dim3(256), 0, stream>>>(
            xq, wq, xscale, wscale, bias, xoc2, woc2, out, T, IN, OUT);
    }
}

// Round 5
// 196.241 us; speedup vs baseline: 1.0929x; 1.0929x over previous
//
#include <hip/hip_runtime.h>
#include <stdint.h>

#define THRESH 6.0f
#define MAXOUT 128
#define NOC 32      // outlier-column capacity in the MFMA extension
#define KEXT 128    // ext row (bf16): x=[hi|lo|hi|0], w=[hi|hi|lo|0]; K=96 used
#define NSLAB 256   // column-max partial slabs

typedef float  floatx4  __attribute__((ext_vector_type(4)));
typedef float  floatx16 __attribute__((ext_vector_type(16)));
typedef short  shortx8  __attribute__((ext_vector_type(8)));
typedef int    intx4    __attribute__((ext_vector_type(4)));
typedef int    intx16   __attribute__((ext_vector_type(16)));
typedef unsigned short ushort_t;

__device__ __forceinline__ ushort_t f2bf(float x) {
    union { float f; uint32_t u; } v; v.f = x;
    return (ushort_t)(v.u >> 16);   // truncation; hi/lo split absorbs the error
}
__device__ __forceinline__ float bf2f(ushort_t b) {
    union { float f; uint32_t u; } v; v.u = ((uint32_t)b) << 16;
    return v.f;
}

// ---------------- K1: column absmax partials (atomic-free, r3-proven) -------
__global__ __launch_bounds__(256) void colmax_part_kernel(
    const float* __restrict__ x, float* __restrict__ partial,
    int* __restrict__ nout, int n4, int rows_per_slab) {
    if (blockIdx.x == 0 && blockIdx.y == 0 && threadIdx.x == 0) *nout = 0;  // init for reduce
    int c4 = blockIdx.x * 256 + threadIdx.x;
    if (c4 >= n4) return;
    int r0 = blockIdx.y * rows_per_slab;
    const floatx4* x4 = (const floatx4*)x;
    floatx4 m = {0.f, 0.f, 0.f, 0.f};
    #pragma unroll 4
    for (int r = r0; r < r0 + rows_per_slab; ++r) {
        floatx4 v = x4[(size_t)r * n4 + c4];
        #pragma unroll
        for (int i = 0; i < 4; ++i) m[i] = fmaxf(m[i], fabsf(v[i]));
    }
    ((floatx4*)partial)[(size_t)blockIdx.y * n4 + c4] = m;
}

// ---------------- K2: reduce partials -> colmax, + ballot compaction --------
__global__ __launch_bounds__(256) void colmax_reduce_kernel(
    const float* __restrict__ partial, float* __restrict__ colmax,
    int* __restrict__ nout, int* __restrict__ oidx, int IN) {
    __shared__ float red[4][64];
    int tid = threadIdx.x, lane = tid & 63, q = tid >> 6;
    int col = blockIdx.x * 64 + lane;
    float m = 0.f;
    for (int s = q; s < NSLAB; s += 4)
        m = fmaxf(m, partial[(size_t)s * IN + col]);
    red[q][lane] = m;
    __syncthreads();
    if (q == 0) {
        m = fmaxf(fmaxf(red[0][lane], red[1][lane]), fmaxf(red[2][lane], red[3][lane]));
        colmax[col] = m;
        bool p = m > THRESH;
        unsigned long long mask = __ballot(p);
        int cnt = __popcll(mask);
        if (cnt > 0) {
            int base = 0;
            if (lane == 0) base = atomicAdd(nout, cnt);
            base = __shfl(base, 0);
            if (p) {
                int pos = base + __popcll(mask & ((1ull << lane) - 1ull));
                if (pos < MAXOUT) oidx[pos] = col;
            }
        }
    }
}

// ---------------- K3: wave-per-row quantization (registers, no LDS) ---------
template<int NITER>   // NITER = IN/256
__global__ __launch_bounds__(256) void quant_kernel(
    const float* __restrict__ x, const float* __restrict__ w,
    const float* __restrict__ colmax,
    const int* __restrict__ oidx, const int* __restrict__ nout,
    int8_t* __restrict__ xq, int8_t* __restrict__ wq,
    float* __restrict__ xscale, float* __restrict__ wscale,
    ushort_t* __restrict__ xoc2, ushort_t* __restrict__ woc2,
    int IN, int T, int TOTAL) {
    int wid = blockIdx.x * 4 + (threadIdx.x >> 6);
    if (wid >= TOTAL) return;
    int lane = threadIdx.x & 63;
    bool isW = wid >= T;
    int r = isW ? wid - T : wid;
    const float* src = (isW ? w : x) + (size_t)r * IN;
    const floatx4* src4 = (const floatx4*)src;
    const floatx4* cm4 = (const floatx4*)colmax;

    floatx4 rowv[NITER];
    float m = 0.f;
    #pragma unroll
    for (int i = 0; i < NITER; ++i) {
        floatx4 v = src4[i * 64 + lane];
        rowv[i] = v;
        if (isW) {
            #pragma unroll
            for (int k = 0; k < 4; ++k) m = fmaxf(m, fabsf(v[k]));
        } else {
            floatx4 cm = cm4[i * 64 + lane];
            #pragma unroll
            for (int k = 0; k < 4; ++k)
                if (!(cm[k] > THRESH)) m = fmaxf(m, fabsf(v[k]));
        }
    }
    #pragma unroll
    for (int off = 32; off; off >>= 1) m = fmaxf(m, __shfl_down(m, off));
    m = __shfl(m, 0);

    float absmax = fmaxf(m, 1e-6f);
    float inv = 127.0f / absmax, scale = absmax / 127.0f;

    uint32_t* dst = (uint32_t*)((isW ? wq : xq) + (size_t)r * IN);
    #pragma unroll
    for (int i = 0; i < NITER; ++i) {
        floatx4 v = rowv[i];
        if (!isW) {
            floatx4 cm = cm4[i * 64 + lane];   // L1-hot reload
            #pragma unroll
            for (int k = 0; k < 4; ++k) if (cm[k] > THRESH) v[k] = 0.f;
        }
        uint32_t pk = 0;
        #pragma unroll
        for (int k = 0; k < 4; ++k) {
            int q = (int)rintf(fminf(fmaxf(v[k] * inv, -127.f), 127.f));
            pk |= ((uint32_t)(uint8_t)(int8_t)q) << (8 * k);
        }
        dst[i * 64 + lane] = pk;
    }
    if (lane == 0) (isW ? wscale : xscale)[r] = scale;

    // extension row [KEXT=128 bf16]: lane computes entries {2*lane, 2*lane+1}
    int no = *nout; if (no > NOC) no = NOC;
    uint32_t pk = 0;
    #pragma unroll
    for (int s = 0; s < 2; ++s) {
        int e = 2 * lane + s;
        int j = e & 31, part = e >> 5;
        ushort_t val = 0;
        if (j < no && part < 3) {
            float v = src[oidx[j]];            // L1/L2-hot scalar re-read
            if (isW) {
                float q = fminf(fmaxf(rintf(v * inv), -127.f), 127.f);
                v = q * scale;                 // dequantized int8 weight
            }
            ushort_t hi = f2bf(v);
            ushort_t lo = f2bf(v - bf2f(hi));
            if (isW) val = (part == 2) ? lo : hi;        // [hi|hi|lo]
            else     val = (part == 1) ? lo : hi;        // [hi|lo|hi]
        }
        pk |= ((uint32_t)val) << (16 * s);
    }
    ushort_t* ext = (isW ? woc2 : xoc2) + (size_t)r * KEXT;
    ((uint32_t*)ext)[lane] = pk;
}

// Generic fallback (IN not a supported multiple)
__global__ __launch_bounds__(256) void quant_generic_kernel(
    const float* __restrict__ x, const float* __restrict__ w,
    const float* __restrict__ colmax,
    const int* __restrict__ oidx, const int* __restrict__ nout,
    int8_t* __restrict__ xq, int8_t* __restrict__ wq,
    float* __restrict__ xscale, float* __restrict__ wscale,
    ushort_t* __restrict__ xoc2, ushort_t* __restrict__ woc2,
    int IN, int T) {
    __shared__ float red[4];
    int bid = blockIdx.x, tid = threadIdx.x;
    bool isW = bid >= T;
    int r = isW ? bid - T : bid;
    const float* src = (isW ? w : x) + (size_t)r * IN;
    float m = 0.f;
    for (int c = tid; c < IN; c += 256) {
        float v = src[c];
        if (isW || !(colmax[c] > THRESH)) m = fmaxf(m, fabsf(v));
    }
    #pragma unroll
    for (int off = 32; off; off >>= 1) m = fmaxf(m, __shfl_down(m, off));
    if ((tid & 63) == 0) red[tid >> 6] = m;
    __syncthreads();
    m = fmaxf(fmaxf(red[0], red[1]), fmaxf(red[2], red[3]));
    float absmax = fmaxf(m, 1e-6f);
    float inv = 127.0f / absmax, scale = absmax / 127.0f;
    int8_t* dst = (isW ? wq : xq) + (size_t)r * IN;
    for (int c = tid; c < IN; c += 256) {
        float v = src[c];
        if (!isW && colmax[c] > THRESH) v = 0.f;
        dst[c] = (int8_t)(int)rintf(fminf(fmaxf(v * inv, -127.f), 127.f));
    }
    if (tid == 0) (isW ? wscale : xscale)[r] = scale;
    int no = *nout; if (no > NOC) no = NOC;
    ushort_t* ext = (isW ? woc2 : xoc2) + (size_t)r * KEXT;
    if (tid < KEXT) {
        int j = tid & 31, part = tid >> 5;
        ushort_t val = 0;
        if (j < no && part < 3) {
            float v = src[oidx[j]];
            if (isW) { float q = fminf(fmaxf(rintf(v * inv), -127.f), 127.f); v = q * scale; }
            ushort_t hi = f2bf(v);
            ushort_t lo = f2bf(v - bf2f(hi));
            if (isW) val = (part == 2) ? lo : hi; else val = (part == 1) ? lo : hi;
        }
        ext[tid] = val;
    }
}

// ---------------- K4: 32x32x32 i8 MFMA GEMM + bf16 32x32x16 ext -------------
// Depth-4 counted-vmcnt pipeline. r3's depth-2 gave 67->56.6us; step audit
// shows ~50% dead time with no saturated pipe -> extend latency cover to ~3
// steps (4 named buffers, 128KB LDS, still 1 block/CU). The ext row is 4
// BKB-tiles (tile 3 all-zeros by construction -> zero-B MFMA is exact), so
// the tile stream NT = nk+4 is 0 mod 4: ext tiles ride the same pipeline
// (removes 3 drain stalls) and the register-only dequant overlaps 8 in-flight
// ext loads. setprio(1) wraps the MFMA clusters (T5).
#define BKB 64   // K-tile bytes/row: 64 int8 (main) == 32 bf16 (ext)

// chunk swizzle: LDS[r][c] holds global[r][c ^ swz(r)] (16B chunks)
__device__ __forceinline__ int swz(int r) { return (r ^ (r >> 2)) & 3; }

template<int TBM, int NTHR>
__device__ __forceinline__ void stage_tiles(const uint8_t* Ab, const uint8_t* Bb,
                                            int strideB, int k0b,
                                            uint8_t* sA, uint8_t* sB, int tid) {
    #pragma unroll
    for (int i = 0; i < (TBM * 4) / NTHR; ++i) {
        int idx = i * NTHR + tid;
        int r = idx >> 2, c = idx & 3;
        int cb = (c ^ swz(r)) * 16;   // fetch permuted chunk -> linear LDS slot
        __builtin_amdgcn_global_load_lds(
            (const __attribute__((address_space(1))) uint32_t*)(Ab + (size_t)r * strideB + k0b + cb),
            (__attribute__((address_space(3))) uint32_t*)(sA + idx * 16), 16, 0, 0);
        __builtin_amdgcn_global_load_lds(
            (const __attribute__((address_space(1))) uint32_t*)(Bb + (size_t)r * strideB + k0b + cb),
            (__attribute__((address_space(3))) uint32_t*)(sB + idx * 16), 16, 0, 0);
    }
}

__device__ __forceinline__ const uint8_t* frag_addr(const uint8_t* s, int row, int C) {
    return s + row * BKB + ((C ^ swz(row)) * 16);
}

union accu_t { intx16 i[2][2]; floatx16 f[2][2]; };

__device__ __forceinline__ void compute_i8(const uint8_t* sA, const uint8_t* sB,
                                           int wm, int wn, int l31, int half,
                                           accu_t& acc) {
    intx4 af[2][2], bf[2][2];
    #pragma unroll
    for (int mt = 0; mt < 2; ++mt)
        #pragma unroll
        for (int ks = 0; ks < 2; ++ks)
            af[mt][ks] = *(const intx4*)frag_addr(sA, wm + mt * 32 + l31, ks * 2 + half);
    #pragma unroll
    for (int nt = 0; nt < 2; ++nt)
        #pragma unroll
        for (int ks = 0; ks < 2; ++ks)
            bf[nt][ks] = *(const intx4*)frag_addr(sB, wn + nt * 32 + l31, ks * 2 + half);
    __builtin_amdgcn_s_setprio(1);
    #pragma unroll
    for (int mt = 0; mt < 2; ++mt)
        #pragma unroll
        for (int nt = 0; nt < 2; ++nt)
            #pragma unroll
            for (int ks = 0; ks < 2; ++ks)
                acc.i[mt][nt] = __builtin_amdgcn_mfma_i32_32x32x32_i8(
                    af[mt][ks], bf[nt][ks], acc.i[mt][nt], 0, 0, 0);
    __builtin_amdgcn_s_setprio(0);
}

__device__ __forceinline__ void compute_bf16(const uint8_t* sA, const uint8_t* sB,
                                             int wm, int wn, int l31, int half,
                                             accu_t& acc) {
    shortx8 af[2][2], bf[2][2];
    #pragma unroll
    for (int mt = 0; mt < 2; ++mt)
        #pragma unroll
        for (int ks = 0; ks < 2; ++ks)
            af[mt][ks] = *(const shortx8*)frag_addr(sA, wm + mt * 32 + l31, ks * 2 + half);
    #pragma unroll
    for (int nt = 0; nt < 2; ++nt)
        #pragma unroll
        for (int ks = 0; ks < 2; ++ks)
            bf[nt][ks] = *(const shortx8*)frag_addr(sB, wn + nt * 32 + l31, ks * 2 + half);
    __builtin_amdgcn_s_setprio(1);
    #pragma unroll
    for (int mt = 0; mt < 2; ++mt)
        #pragma unroll
        for (int nt = 0; nt < 2; ++nt)
            #pragma unroll
            for (int ks = 0; ks < 2; ++ks)
                acc.f[mt][nt] = __builtin_amdgcn_mfma_f32_32x32x16_bf16(
                    af[mt][ks], bf[nt][ks], acc.f[mt][nt], 0, 0, 0);
    __builtin_amdgcn_s_setprio(0);
}

// Depth-4 pipelined big-path kernel: requires (TBM*4)/NTHR == 1
// (2 loads/thread/stage), nk % 4 == 0, nk >= 8.
template<int TBM, int TBN, int NTHR>
__global__ __launch_bounds__(NTHR) void gemm_pipe_kernel(
    const int8_t* __restrict__ A,   // xq [T, IN]
    const int8_t* __restrict__ B,   // wq [OUT, IN]
    const float* __restrict__ xscale, const float* __restrict__ wscale,
    const float* __restrict__ bias,
    const ushort_t* __restrict__ xoc2,  // [T, KEXT] bf16
    const ushort_t* __restrict__ woc2,  // [OUT, KEXT] bf16
    float* __restrict__ out, int T, int IN, int OUT)
{
    static_assert((TBM * 4) / NTHR == 1, "vmcnt counting assumes 2 loads/thread/stage");
    __shared__ __attribute__((aligned(16))) uint8_t sA0[TBM * BKB];
    __shared__ __attribute__((aligned(16))) uint8_t sB0[TBN * BKB];
    __shared__ __attribute__((aligned(16))) uint8_t sA1[TBM * BKB];
    __shared__ __attribute__((aligned(16))) uint8_t sB1[TBN * BKB];
    __shared__ __attribute__((aligned(16))) uint8_t sA2[TBM * BKB];
    __shared__ __attribute__((aligned(16))) uint8_t sB2[TBN * BKB];
    __shared__ __attribute__((aligned(16))) uint8_t sA3[TBM * BKB];
    __shared__ __attribute__((aligned(16))) uint8_t sB3[TBN * BKB];

    int tid = threadIdx.x;

    // bijective XCD-aware block swizzle (nwg % 8 == 0 on the big path)
    int nwg = gridDim.x * gridDim.y;
    int bid = blockIdx.y * gridDim.x + blockIdx.x;
    if ((nwg & 7) == 0) {
        int cpx = nwg >> 3;
        bid = (bid & 7) * cpx + (bid >> 3);
    }
    int bx = bid % gridDim.x, by = bid / gridDim.x;
    int m0 = by * TBM, n0 = bx * TBN;

    int lane = tid & 63, w = tid >> 6;
    constexpr int WC = TBN / 64;            // waves along N
    int wm = (w / WC) * 64, wn = (w % WC) * 64;
    int l31 = lane & 31, half = lane >> 5;

    accu_t acc;
    #pragma unroll
    for (int mt = 0; mt < 2; ++mt)
        #pragma unroll
        for (int nt = 0; nt < 2; ++nt)
            acc.i[mt][nt] = (intx16)(0);

    const uint8_t* Ab = (const uint8_t*)A + (size_t)m0 * IN;
    const uint8_t* Bb = (const uint8_t*)B + (size_t)n0 * IN;
    const uint8_t* Ae = (const uint8_t*)xoc2 + (size_t)m0 * (KEXT * 2);
    const uint8_t* Be = (const uint8_t*)woc2 + (size_t)n0 * (KEXT * 2);

    int nk = IN / BKB;   // % 4 == 0, >= 8

    // prologue: four stages in flight (2 loads/thread each -> 8 outstanding)
    stage_tiles<TBM, NTHR>(Ab, Bb, IN, 0 * BKB, sA0, sB0, tid);
    stage_tiles<TBM, NTHR>(Ab, Bb, IN, 1 * BKB, sA1, sB1, tid);
    stage_tiles<TBM, NTHR>(Ab, Bb, IN, 2 * BKB, sA2, sB2, tid);
    stage_tiles<TBM, NTHR>(Ab, Bb, IN, 3 * BKB, sA3, sB3, tid);

    // main loop: tiles 0..nk-5; last 4 main tiles peeled as transition
    int t = 0;
    for (; t + 4 < nk; t += 4) {
        asm volatile("s_waitcnt vmcnt(6)" ::: "memory");
        __builtin_amdgcn_s_barrier();
        compute_i8(sA0, sB0, wm, wn, l31, half, acc);
        __builtin_amdgcn_s_barrier();
        stage_tiles<TBM, NTHR>(Ab, Bb, IN, (t + 4) * BKB, sA0, sB0, tid);

        asm volatile("s_waitcnt vmcnt(6)" ::: "memory");
        __builtin_amdgcn_s_barrier();
        compute_i8(sA1, sB1, wm, wn, l31, half, acc);
        __builtin_amdgcn_s_barrier();
        stage_tiles<TBM, NTHR>(Ab, Bb, IN, (t + 5) * BKB, sA1, sB1, tid);

        asm volatile("s_waitcnt vmcnt(6)" ::: "memory");
        __builtin_amdgcn_s_barrier();
        compute_i8(sA2, sB2, wm, wn, l31, half, acc);
        __builtin_amdgcn_s_barrier();
        stage_tiles<TBM, NTHR>(Ab, Bb, IN, (t + 6) * BKB, sA2, sB2, tid);

        asm volatile("s_waitcnt vmcnt(6)" ::: "memory");
        __builtin_amdgcn_s_barrier();
        compute_i8(sA3, sB3, wm, wn, l31, half, acc);
        __builtin_amdgcn_s_barrier();
        stage_tiles<TBM, NTHR>(Ab, Bb, IN, (t + 7) * BKB, sA3, sB3, tid);
    }

    // transition: compute last 4 main tiles, stage the 4 ext tiles
    asm volatile("s_waitcnt vmcnt(6)" ::: "memory");
    __builtin_amdgcn_s_barrier();
    compute_i8(sA0, sB0, wm, wn, l31, half, acc);
    __builtin_amdgcn_s_barrier();
    stage_tiles<TBM, NTHR>(Ae, Be, KEXT * 2, 0 * BKB, sA0, sB0, tid);

    asm volatile("s_waitcnt vmcnt(6)" ::: "memory");
    __builtin_amdgcn_s_barrier();
    compute_i8(sA1, sB1, wm, wn, l31, half, acc);
    __builtin_amdgcn_s_barrier();
    stage_tiles<TBM, NTHR>(Ae, Be, KEXT * 2, 1 * BKB, sA1, sB1, tid);

    asm volatile("s_waitcnt vmcnt(6)" ::: "memory");
    __builtin_amdgcn_s_barrier();
    compute_i8(sA2, sB2, wm, wn, l31, half, acc);
    __builtin_amdgcn_s_barrier();
    stage_tiles<TBM, NTHR>(Ae, Be, KEXT * 2, 2 * BKB, sA2, sB2, tid);

    asm volatile("s_waitcnt vmcnt(6)" ::: "memory");
    __builtin_amdgcn_s_barrier();
    compute_i8(sA3, sB3, wm, wn, l31, half, acc);
    __builtin_amdgcn_s_barrier();
    stage_tiles<TBM, NTHR>(Ae, Be, KEXT * 2, 3 * BKB, sA3, sB3, tid);

    // register-only dequant + bias while 8 ext loads are in flight:
    // f = (float)i * xs * ws + bias
    // C/D 32x32 layout: col=lane&31, row=(reg&3)+8*(reg>>2)+4*(lane>>5)
    #pragma unroll
    for (int mt = 0; mt < 2; ++mt) {
        floatx4 xsg[4];
        #pragma unroll
        for (int g = 0; g < 4; ++g)
            xsg[g] = *(const floatx4*)(xscale + m0 + wm + mt * 32 + g * 8 + half * 4);
        #pragma unroll
        for (int nt = 0; nt < 2; ++nt) {
            int o = n0 + wn + nt * 32 + l31;
            float s = wscale[o], bv = bias[o];
            #pragma unroll
            for (int reg = 0; reg < 16; ++reg)
                acc.f[mt][nt][reg] =
                    (float)acc.i[mt][nt][reg] * (xsg[reg >> 2][reg & 3] * s) + bv;
        }
    }

    // ext phase: 4 bf16 tiles (tile 3 is all-zeros -> exact no-op MFMA)
    asm volatile("s_waitcnt vmcnt(6)" ::: "memory");
    __builtin_amdgcn_s_barrier();
    compute_bf16(sA0, sB0, wm, wn, l31, half, acc);
    asm volatile("s_waitcnt vmcnt(4)" ::: "memory");
    __builtin_amdgcn_s_barrier();
    compute_bf16(sA1, sB1, wm, wn, l31, half, acc);
    asm volatile("s_waitcnt vmcnt(2)" ::: "memory");
    __builtin_amdgcn_s_barrier();
    compute_bf16(sA2, sB2, wm, wn, l31, half, acc);
    asm volatile("s_waitcnt vmcnt(0)" ::: "memory");
    __builtin_amdgcn_s_barrier();
    compute_bf16(sA3, sB3, wm, wn, l31, half, acc);

    // store
    #pragma unroll
    for (int mt = 0; mt < 2; ++mt)
        #pragma unroll
        for (int nt = 0; nt < 2; ++nt) {
            int o = n0 + wn + nt * 32 + l31;
            #pragma unroll
            for (int reg = 0; reg < 16; ++reg) {
                int row = (reg & 3) + 8 * (reg >> 2) + 4 * half;
                int tr = m0 + wm + mt * 32 + row;
                out[(size_t)tr * OUT + o] = acc.f[mt][nt][reg];
            }
        }
}

// Fallback (non-multiple shapes): round-0 verified structure
template<int TBM, int TBN, int NTHR>
__global__ __launch_bounds__(NTHR) void gemm_kernel(
    const int8_t* __restrict__ A, const int8_t* __restrict__ B,
    const float* __restrict__ xscale, const float* __restrict__ wscale,
    const float* __restrict__ bias,
    const ushort_t* __restrict__ xoc2, const ushort_t* __restrict__ woc2,
    float* __restrict__ out, int T, int IN, int OUT)
{
    __shared__ __attribute__((aligned(16))) uint8_t sA[TBM * BKB];
    __shared__ __attribute__((aligned(16))) uint8_t sB[TBN * BKB];

    int tid = threadIdx.x;
    int m0 = blockIdx.y * TBM, n0 = blockIdx.x * TBN;
    int lane = tid & 63, w = tid >> 6;
    constexpr int WC = TBN / 64;
    int wm = (w / WC) * 64, wn = (w % WC) * 64;
    int l31 = lane & 31, half = lane >> 5;

    accu_t acc;
    #pragma unroll
    for (int mt = 0; mt < 2; ++mt)
        #pragma unroll
        for (int nt = 0; nt < 2; ++nt)
            acc.i[mt][nt] = (intx16)(0);

    const uint8_t* Ab = (const uint8_t*)A + (size_t)m0 * IN;
    const uint8_t* Bb = (const uint8_t*)B + (size_t)n0 * IN;

    int nk = IN / BKB;
    for (int kt = 0; kt < nk; ++kt) {
        __syncthreads();
        stage_tiles<TBM, NTHR>(Ab, Bb, IN, kt * BKB, sA, sB, tid);
        __syncthreads();
        compute_i8(sA, sB, wm, wn, l31, half, acc);
    }

    #pragma unroll
    for (int mt = 0; mt < 2; ++mt) {
        floatx4 xsg[4];
        #pragma unroll
        for (int g = 0; g < 4; ++g)
            xsg[g] = *(const floatx4*)(xscale + m0 + wm + mt * 32 + g * 8 + half * 4);
        #pragma unroll
        for (int nt = 0; nt < 2; ++nt) {
            int o = n0 + wn + nt * 32 + l31;
            float s = wscale[o], bv = bias[o];
            #pragma unroll
            for (int reg = 0; reg < 16; ++reg)
                acc.f[mt][nt][reg] =
                    (float)acc.i[mt][nt][reg] * (xsg[reg >> 2][reg & 3] * s) + bv;
        }
    }

    const uint8_t* Ae = (const uint8_t*)xoc2 + (size_t)m0 * (KEXT * 2);
    const uint8_t* Be = (const uint8_t*)woc2 + (size_t)n0 * (KEXT * 2);
    #pragma unroll
    for (int kt = 0; kt < 3; ++kt) {
        __syncthreads();
        stage_tiles<TBM, NTHR>(Ae, Be, KEXT * 2, kt * BKB, sA, sB, tid);
        __syncthreads();
        compute_bf16(sA, sB, wm, wn, l31, half, acc);
    }

    #pragma unroll
    for (int mt = 0; mt < 2; ++mt)
        #pragma unroll
        for (int nt = 0; nt < 2; ++nt) {
            int o = n0 + wn + nt * 32 + l31;
            #pragma unroll
            for (int reg = 0; reg < 16; ++reg) {
                int row = (reg & 3) + 8 * (reg >> 2) + 4 * half;
                int t = m0 + wm + mt * 32 + row;
                out[(size_t)t * OUT + o] = acc.f[mt][nt][reg];
            }
        }
}

extern "C" void kernel_launch(void* const* d_in, const int* in_sizes, int n_in,
                              void* d_out, int out_size, void* d_ws, size_t ws_size,
                              hipStream_t stream) {
    const float* x    = (const float*)d_in[0];
    const float* wgt  = (const float*)d_in[1];
    const float* bias = (const float*)d_in[2];
    float* out = (float*)d_out;

    int OUT = in_sizes[2];
    int IN  = in_sizes[1] / OUT;
    int T   = in_sizes[0] / IN;

    char* p = (char*)d_ws;
    int8_t* xq     = (int8_t*)p;   p += (size_t)T * IN;
    int8_t* wq     = (int8_t*)p;   p += (size_t)OUT * IN;
    ushort_t* xoc2 = (ushort_t*)p; p += (size_t)T * KEXT * 2;
    ushort_t* woc2 = (ushort_t*)p; p += (size_t)OUT * KEXT * 2;
    float* wscale  = (float*)p;    p += (size_t)OUT * 4;
    float* xscale  = (float*)p;    p += (size_t)T * 4;
    float* colmax  = (float*)p;    p += (size_t)IN * 4;
    int*   nout    = (int*)p;      p += 256;
    int*   oidx    = (int*)p;      p += MAXOUT * 4;
    float* partial = (float*)p;    p += (size_t)NSLAB * IN * 4;

    int n4 = IN / 4;
    int gx = (n4 + 255) / 256;
    colmax_part_kernel<<<dim3(gx, NSLAB), dim3(256), 0, stream>>>(
        x, partial, nout, n4, T / NSLAB);

    colmax_reduce_kernel<<<dim3(IN / 64), dim3(256), 0, stream>>>(
        partial, colmax, nout, oidx, IN);

    int TOTAL = T + OUT;
    int niter = IN / 256;
    bool ok = (IN % 256 == 0) && (niter == 4 || niter == 8 || niter == 16);
    if (ok) {
        int blocks = (TOTAL + 3) / 4;
        switch (niter) {
        case 4:
            quant_kernel<4><<<dim3(blocks), dim3(256), 0, stream>>>(
                x, wgt, colmax, oidx, nout, xq, wq, xscale, wscale, xoc2, woc2, IN, T, TOTAL);
            break;
        case 8:
            quant_kernel<8><<<dim3(blocks), dim3(256), 0, stream>>>(
                x, wgt, colmax, oidx, nout, xq, wq, xscale, wscale, xoc2, woc2, IN, T, TOTAL);
            break;
        default:
            quant_kernel<16><<<dim3(blocks), dim3(256), 0, stream>>>(
                x, wgt, colmax, oidx, nout, xq, wq, xscale, wscale, xoc2, woc2, IN, T, TOTAL);
            break;
        }
    } else {
        quant_generic_kernel<<<dim3(TOTAL), dim3(256), 0, stream>>>(
            x, wgt, colmax, oidx, nout, xq, wq, xscale, wscale, xoc2, woc2, IN, T);
    }

    int nk = IN / BKB;
    bool big = (T % 256 == 0) && (OUT % 256 == 0) && (IN % BKB == 0)
               && (nk % 4 == 0) && (nk >= 8);
    if (big) {
        gemm_pipe_kernel<256, 256, 1024><<<dim3(OUT / 256, T / 256), dim3(1024), 0, stream>>>(
            xq, wq, xscale, wscale, bias, xoc2, woc2, out, T, IN, OUT);
    } else {
        gemm_kernel<128, 128, 256><<<dim3(OUT / 128, T / 128), dim3(256), 0, stream>>>(
            xq, wq, xscale, wscale, bias, xoc2, woc2, out, T, IN, OUT);
    }
}